// Round 13
// baseline (214.478 us; speedup 1.0000x reference)
//
#include <hip/hip_runtime.h>
#include <stdint.h>

#define DM 1024
#define SEQ 2048
#define NTOK 4096
#define HD 64

typedef __bf16 bf16x8 __attribute__((ext_vector_type(8)));
typedef float f32x4 __attribute__((ext_vector_type(4)));
typedef uint32_t u32x2 __attribute__((ext_vector_type(2)));
typedef uint32_t u32x4 __attribute__((ext_vector_type(4)));

#if __has_builtin(__builtin_amdgcn_exp2f)
#define EXP2F(x) __builtin_amdgcn_exp2f(x)
#else
#define EXP2F(x) exp2f(x)
#endif

// wave-staging 16B load: global -> LDS (wave-uniform base + lane*16).
// Host pass / no-builtin fallback keeps the source parseable everywhere.
__device__ __forceinline__ void gll16f(const char* g, char* lds_wave_base, int lane) {
#if __has_builtin(__builtin_amdgcn_global_load_lds)
  __builtin_amdgcn_global_load_lds(
      (const __attribute__((address_space(1))) void*)g,
      (__attribute__((address_space(3))) void*)lds_wave_base, 16, 0, 0);
#else
  *(bf16x8*)(lds_wave_base + lane * 16) = *(const bf16x8*)g;
#endif
}

__device__ __forceinline__ uint16_t f2bf(float f) {
  uint32_t x = __float_as_uint(f);
  return (uint16_t)((x + 0x7fffu + ((x >> 16) & 1u)) >> 16);
}

// packed f32 pair -> 2x bf16 dword (lo = a, hi = b)
__device__ __forceinline__ uint32_t cvtpk(float a, float b) {
  uint32_t r;
  asm("v_cvt_pk_bf16_f32 %0, %1, %2" : "=v"(r) : "v"(a), "v"(b));
  return r;
}

__device__ __forceinline__ bf16x8 mk8(uint32_t a, uint32_t b, uint32_t c, uint32_t d) {
  u32x4 t = {a, b, c, d};
  return __builtin_bit_cast(bf16x8, t);
}

// ---------------- prep: x->bf16 (blocks 0..4095) + 4x W transpose ------------
__global__ void prep_kernel(const float* __restrict__ x, uint16_t* __restrict__ xb,
                            const float* __restrict__ W0, const float* __restrict__ W1,
                            const float* __restrict__ W2, const float* __restrict__ W3,
                            uint16_t* __restrict__ T0, uint16_t* __restrict__ T1,
                            uint16_t* __restrict__ T2, uint16_t* __restrict__ T3) {
  __shared__ float t[32][33];
  int bid = blockIdx.x;
  if (bid < 4096) {
    int i = (bid * 256 + threadIdx.x) * 4;
    float4 v = *(const float4*)&x[i];
    uint64_t pk = (uint64_t)f2bf(v.x) | ((uint64_t)f2bf(v.y) << 16) |
                  ((uint64_t)f2bf(v.z) << 32) | ((uint64_t)f2bf(v.w) << 48);
    *(uint64_t*)&xb[i] = pk;
    return;
  }
  int b2 = bid - 4096;
  int zz = b2 >> 10, rr = b2 & 1023;
  const float* W = (zz == 0) ? W0 : (zz == 1) ? W1 : (zz == 2) ? W2 : W3;
  uint16_t* T = (zz == 0) ? T0 : (zz == 1) ? T1 : (zz == 2) ? T2 : T3;
  int tx = threadIdx.x & 31, ty = threadIdx.x >> 5;
  int nb = (rr & 31) * 32, kb = (rr >> 5) * 32;
#pragma unroll
  for (int i = 0; i < 4; i++)
    t[ty + i * 8][tx] = W[(kb + ty + i * 8) * DM + nb + tx];
  __syncthreads();
#pragma unroll
  for (int i = 0; i < 4; i++)
    T[(nb + ty + i * 8) * DM + kb + tx] = f2bf(t[tx][ty + i * 8]);
}

// ---------------- GEMM body: C[4096, 128-col tile] = A @ Bt^T + bias ---------
// Tile = (MF*32) rows x 128 cols, BK=64, 4 waves as 2x2, wave tile (MF*16)x64.
// LDS rows are 128B -> frag reads XOR-swizzled (byte ^ (row&7)<<4), GLL source
// pre-swizzled to match (both-sides rule).
// MODE 0: out bf16 [bh][s][64] scaled   MODE 1: out bf16 [bh][d][s-mu'] (v'')
// MODE 2: out fp32 [row][col]
template <int MODE, int MF>
__device__ __forceinline__ void gemm_body(const uint16_t* __restrict__ A,
                                          const uint16_t* __restrict__ Bt,
                                          const float* __restrict__ bias, float scale,
                                          void* __restrict__ out, uint16_t* lds,
                                          int bx, int by) {
  const int tid = threadIdx.x;
  const int w = tid >> 6, lane = tid & 63;
  const int wr = w >> 1, wc = w & 1;
  const int a15 = lane & 15, a4 = lane >> 4;
  const int m0 = by * (MF * 32), n0 = bx * 128;
  char* lgA = (char*)lds;                 // MF*32 rows x 128B
  char* lgB = (char*)(lds + MF * 2048);   // 128 rows x 128B
  f32x4 acc[MF][4];
#pragma unroll
  for (int m = 0; m < MF; m++)
#pragma unroll
    for (int n = 0; n < 4; n++) acc[m][n] = (f32x4){0.f, 0.f, 0.f, 0.f};

  const char* Ag = (const char*)(A + (size_t)m0 * DM);
  const char* Bg = (const char*)(Bt + (size_t)n0 * DM);
  const int srow = lane >> 3;                        // row-within-8 for staging
  const int scol = ((lane & 7) * 16) ^ (srow << 4);  // pre-swizzled source col
  const int swz = (a15 & 7) << 4;                    // read-side XOR

  for (int k0 = 0; k0 < DM; k0 += 64) {
#pragma unroll
    for (int c = 0; c < MF; c++) {
      int ro = w * (MF * 8) + c * 8 + srow;
      gll16f(Ag + (size_t)ro * (DM * 2) + k0 * 2 + scol, lgA + (w * MF + c) * 1024, lane);
    }
#pragma unroll
    for (int c = 0; c < 4; c++) {
      int ro = w * 32 + c * 8 + srow;
      gll16f(Bg + (size_t)ro * (DM * 2) + k0 * 2 + scol, lgB + (w * 4 + c) * 1024, lane);
    }
    __syncthreads();
    bf16x8 af[MF][2], bfr[4][2];
#pragma unroll
    for (int m = 0; m < MF; m++)
#pragma unroll
      for (int kk = 0; kk < 2; kk++)
        af[m][kk] = *(const bf16x8*)(lgA + (wr * (MF * 16) + m * 16 + a15) * 128 +
                                     ((kk * 64 + a4 * 16) ^ swz));
#pragma unroll
    for (int n = 0; n < 4; n++)
#pragma unroll
      for (int kk = 0; kk < 2; kk++)
        bfr[n][kk] = *(const bf16x8*)(lgB + (wc * 64 + n * 16 + a15) * 128 +
                                      ((kk * 64 + a4 * 16) ^ swz));
#pragma unroll
    for (int kk = 0; kk < 2; kk++)
#pragma unroll
      for (int m = 0; m < MF; m++)
#pragma unroll
        for (int n = 0; n < 4; n++)
          acc[m][n] = __builtin_amdgcn_mfma_f32_16x16x32_bf16(af[m][kk], bfr[n][kk],
                                                              acc[m][n], 0, 0, 0);
    __syncthreads();
  }

#pragma unroll
  for (int m = 0; m < MF; m++) {
#pragma unroll
    for (int n = 0; n < 4; n++) {
      int gr0 = m0 + wr * (MF * 16) + m * 16 + a4 * 4;
      int col = n0 + wc * 64 + n * 16 + a15;
      float bv = bias[col];
      if constexpr (MODE == 2) {
        float* O = (float*)out;
#pragma unroll
        for (int j = 0; j < 4; j++)
          O[(size_t)(gr0 + j) * DM + col] = acc[m][n][j] + bv;
      } else if constexpr (MODE == 0) {
        uint16_t* O = (uint16_t*)out;
        int h = col >> 6, d = col & 63;
#pragma unroll
        for (int j = 0; j < 4; j++) {
          int gr = gr0 + j;
          int b = gr >> 11, s = gr & 2047;
          O[((size_t)(((b << 4) + h)) * SEQ + s) * HD + d] = f2bf((acc[m][n][j] + bv) * scale);
        }
      } else {
        // V'' layout: [bh][d][2048], within each 64-key group keys permuted:
        // pos = kb*32 + g*8 + ehi*4 + j  holds key k = kb*32 + 16*ehi + 4g + j
        uint16_t* O = (uint16_t*)out;
        int h = col >> 6, d = col & 63;
        int b = gr0 >> 11, s0 = gr0 & 2047;
        int it = s0 >> 6, s6 = s0 & 63;
        int pos = (s6 >> 5) * 32 + ((s6 >> 2) & 3) * 8 + ((s6 >> 4) & 1) * 4;
        uint64_t pk = 0;
#pragma unroll
        for (int j = 0; j < 4; j++)
          pk |= (uint64_t)f2bf(acc[m][n][j] + bv) << (16 * j);
        *(uint64_t*)&O[((size_t)(((b << 4) + h)) * HD + d) * SEQ + it * 64 + pos] = pk;
      }
    }
  }
}

#define CS_SCALE 0.180336880f  // log2(e)/sqrt(hd) folded into q

// flat grid 768, XCD-chunked: each XCD gets 96 consecutive (z,y,x) blocks
__global__ __launch_bounds__(256, 2) void gemm_qkv_kernel(
    const uint16_t* __restrict__ xb, const uint16_t* __restrict__ wtq,
    const uint16_t* __restrict__ wtk, const uint16_t* __restrict__ wtv,
    const float* __restrict__ bq, const float* __restrict__ bk,
    const float* __restrict__ bv, uint16_t* __restrict__ qo,
    uint16_t* __restrict__ ko, uint16_t* __restrict__ vto) {
  __shared__ __attribute__((aligned(16))) uint16_t lds[16384];  // 32 KB
  int id = blockIdx.x;
  int swz = (id & 7) * 96 + (id >> 3);
  int z = swz >> 8, r = swz & 255;
  int by = r >> 3, bx = r & 7;
  if (z == 0)      gemm_body<0, 4>(xb, wtq, bq, CS_SCALE, qo, lds, bx, by);
  else if (z == 1) gemm_body<0, 4>(xb, wtk, bk, 1.0f, ko, lds, bx, by);
  else             gemm_body<1, 4>(xb, wtv, bv, 1.0f, vto, lds, bx, by);
}

// flat grid 512, XCD-chunked (64 blocks per XCD)
__global__ __launch_bounds__(256, 2) void gemm_out_kernel(
    const uint16_t* __restrict__ ctx, const uint16_t* __restrict__ wto,
    const float* __restrict__ bo, float* __restrict__ out) {
  __shared__ __attribute__((aligned(16))) uint16_t lds[12288];  // 24 KB
  int id = blockIdx.x;
  int swz = (id & 7) * 64 + (id >> 3);
  int by = swz >> 3, bx = swz & 7;
  gemm_body<2, 2>(ctx, wto, bo, 1.0f, out, lds, bx, by);
}

// ---------------- attention (8 waves: 2 K-groups x 4 q-waves, LDS combine) ---
// q (pre-scaled by CS), k: [bh][s][64]   v'': [bh][d][2048 mu'-permuted]
// 512 blocks x 512 threads -> 2 blocks/CU = 16 waves/CU = 4 waves/SIMD.
// Group g handles keys g*1024..g*1024+1023 (16 tiles), own dbuf staging
// region; fixed-scale exp2 softmax => partials combine linearly: group 1
// writes O,l to LDS at the end, group 0 adds, divides, stores ctx.
__global__ __launch_bounds__(512, 4) void attn_kernel(
    const uint16_t* __restrict__ qg, const uint16_t* __restrict__ kg,
    const uint16_t* __restrict__ vtg, uint16_t* __restrict__ ctx) {
  const int tid = threadIdx.x;
  const int w = tid >> 6, l = tid & 63;
  const int grp = w >> 2, wq = w & 3;
  const int l15 = l & 15, g = l >> 4;
  // XCD swizzle: 64 consecutive wg per XCD -> 4 bh per XCD (KV fits L2)
  int id = blockIdx.x;
  int wg = (id & 7) * 64 + (id >> 3);
  int bh = wg >> 4, qb = wg & 15;
  const int q0 = qb * 128 + wq * 32;
  const int kbase = grp * 16;  // this group's first tile (of 32 total)
  const uint16_t* Qb = qg + (size_t)bh * SEQ * HD;
  const char* Kc = (const char*)(kg + (size_t)bh * SEQ * HD);
  const char* Vc = (const char*)(vtg + (size_t)bh * HD * SEQ);

  // [grp][buf][ K 8KB | V 8KB ] = 64 KB; reused as combine buffer at the end
  __shared__ __attribute__((aligned(16))) char SMEM[65536];
  char* Kr0 = SMEM + grp * 32768;            // buf 0 K
  // buf b: K at Kr0 + b*16384, V at Kr0 + b*16384 + 8192

  // staging: 64 rows x 128B per tile; wave wq covers rows wq*16 + i*8 .. +8
  const int srow = l >> 3;                          // 0..7 (row&7 == srow)
  const int scolx = ((l & 7) * 16) ^ (srow << 4);   // swizzled source col

#define STAGE(BUF, IT)                                                         \
  {                                                                            \
    const int it1_ = (IT);                                                     \
    _Pragma("unroll") for (int i = 0; i < 2; i++) {                            \
      int r = wq * 16 + i * 8 + srow;                                          \
      gll16f(Kc + (size_t)(it1_ * 64 + r) * 128 + scolx,                       \
             Kr0 + (BUF) * 16384 + wq * 2048 + i * 1024, l);                   \
      gll16f(Vc + (size_t)r * (SEQ * 2) + it1_ * 128 + scolx,                  \
             Kr0 + (BUF) * 16384 + 8192 + wq * 2048 + i * 1024, l);            \
    }                                                                          \
  }

  // Q B-frags (hoisted): bq[qs][ks] slot(g,e) = Q[q0+qs*16+l15][ks*32+g*8+e]
  bf16x8 bq[2][2];
#pragma unroll
  for (int qs = 0; qs < 2; qs++)
#pragma unroll
    for (int ks = 0; ks < 2; ks++)
      bq[qs][ks] = *(const bf16x8*)&Qb[(size_t)(q0 + qs * 16 + l15) * HD + ks * 32 + g * 8];

  f32x4 o[4][2];  // [dt][qs]
#pragma unroll
  for (int dt = 0; dt < 4; dt++)
#pragma unroll
    for (int qs = 0; qs < 2; qs++) o[dt][qs] = (f32x4){0.f, 0.f, 0.f, 0.f};
  f32x4 ol0 = {0.f, 0.f, 0.f, 0.f}, ol1 = {0.f, 0.f, 0.f, 0.f};  // denominators
  const int swz = (l15 & 7) << 4;               // read-side XOR
  const uint32_t ONE2 = 0x3F803F80u;            // 2x bf16 1.0
  const bf16x8 aones = mk8(ONE2, ONE2, ONE2, ONE2);

#define TILE(ITL, BI, BN)                                                      \
  {                                                                            \
    const int itl_ = (ITL);                                                    \
    if (itl_ + 1 < 16) {                                                       \
      STAGE(BN, kbase + itl_ + 1);                                             \
      asm volatile("s_waitcnt vmcnt(4)\n\ts_barrier" ::: "memory");            \
    } else {                                                                   \
      asm volatile("s_waitcnt vmcnt(0)\n\ts_barrier" ::: "memory");            \
    }                                                                          \
    const char* Kb_ = Kr0 + (BI) * 16384;                                      \
    const char* Vb_ = Kb_ + 8192;                                              \
    /* K A-frags from LDS (swizzled) */                                        \
    bf16x8 ak[4][2];                                                           \
    _Pragma("unroll") for (int kt = 0; kt < 4; kt++)                           \
        _Pragma("unroll") for (int ks = 0; ks < 2; ks++)                       \
            ak[kt][ks] = *(const bf16x8*)&Kb_[(kt * 16 + l15) * 128 +          \
                                              ((ks * 64 + g * 16) ^ swz)];     \
    /* V A-frags (mu' baked into V''): single b128 per frag */                 \
    bf16x8 av[4][2];                                                           \
    _Pragma("unroll") for (int dt = 0; dt < 4; dt++)                           \
        _Pragma("unroll") for (int kb = 0; kb < 2; kb++)                       \
            av[dt][kb] = *(const bf16x8*)&Vb_[(dt * 16 + l15) * 128 +          \
                                              ((kb * 64 + g * 16) ^ swz)];     \
    /* S^T[k][q] (q pre-scaled by CS) */                                       \
    f32x4 s[2][4];                                                             \
    _Pragma("unroll") for (int qs = 0; qs < 2; qs++)                           \
        _Pragma("unroll") for (int kt = 0; kt < 4; kt++)                       \
            s[qs][kt] = (f32x4){0.f, 0.f, 0.f, 0.f};                           \
    __builtin_amdgcn_s_setprio(1);                                             \
    _Pragma("unroll") for (int kt = 0; kt < 4; kt++)                           \
        _Pragma("unroll") for (int ks = 0; ks < 2; ks++) {                     \
      s[0][kt] = __builtin_amdgcn_mfma_f32_16x16x32_bf16(ak[kt][ks], bq[0][ks], s[0][kt], 0, 0, 0); \
      s[1][kt] = __builtin_amdgcn_mfma_f32_16x16x32_bf16(ak[kt][ks], bq[1][ks], s[1][kt], 0, 0, 0); \
    }                                                                          \
    __builtin_amdgcn_s_setprio(0);                                             \
    /* P = exp2(s); pack B-frags via mu' (no fma, no max, no cross-lane) */    \
    float p0[4][4], p1[4][4];                                                  \
    _Pragma("unroll") for (int kt = 0; kt < 4; kt++)                           \
        _Pragma("unroll") for (int j = 0; j < 4; j++) {                        \
      p0[kt][j] = EXP2F(s[0][kt][j]);                                          \
      p1[kt][j] = EXP2F(s[1][kt][j]);                                          \
    }                                                                          \
    bf16x8 bp0[2], bp1[2];                                                     \
    _Pragma("unroll") for (int kb = 0; kb < 2; kb++) {                         \
      bp0[kb] = mk8(cvtpk(p0[2 * kb][0], p0[2 * kb][1]),                       \
                    cvtpk(p0[2 * kb][2], p0[2 * kb][3]),                       \
                    cvtpk(p0[2 * kb + 1][0], p0[2 * kb + 1][1]),               \
                    cvtpk(p0[2 * kb + 1][2], p0[2 * kb + 1][3]));              \
      bp1[kb] = mk8(cvtpk(p1[2 * kb][0], p1[2 * kb][1]),                       \
                    cvtpk(p1[2 * kb][2], p1[2 * kb][3]),                       \
                    cvtpk(p1[2 * kb + 1][0], p1[2 * kb + 1][1]),               \
                    cvtpk(p1[2 * kb + 1][2], p1[2 * kb + 1][3]));              \
    }                                                                          \
    /* O^T += V . P ; l += 1 . P */                                            \
    __builtin_amdgcn_s_setprio(1);                                             \
    _Pragma("unroll") for (int dt = 0; dt < 4; dt++)                           \
        _Pragma("unroll") for (int kb = 0; kb < 2; kb++) {                     \
      o[dt][0] = __builtin_amdgcn_mfma_f32_16x16x32_bf16(av[dt][kb], bp0[kb], o[dt][0], 0, 0, 0); \
      o[dt][1] = __builtin_amdgcn_mfma_f32_16x16x32_bf16(av[dt][kb], bp1[kb], o[dt][1], 0, 0, 0); \
    }                                                                          \
    _Pragma("unroll") for (int kb = 0; kb < 2; kb++) {                         \
      ol0 = __builtin_amdgcn_mfma_f32_16x16x32_bf16(aones, bp0[kb], ol0, 0, 0, 0); \
      ol1 = __builtin_amdgcn_mfma_f32_16x16x32_bf16(aones, bp1[kb], ol1, 0, 0, 0); \
    }                                                                          \
    __builtin_amdgcn_s_setprio(0);                                             \
    asm volatile("s_waitcnt lgkmcnt(0)\n\ts_barrier" ::: "memory");            \
  }

  // prologue: stage this group's first tile into buf 0
  STAGE(0, kbase);
  asm volatile("s_waitcnt vmcnt(0)\n\ts_barrier" ::: "memory");

  for (int it2 = 0; it2 < 8; ++it2) {
    TILE(2 * it2, 0, 1);
    TILE(2 * it2 + 1, 1, 0);
  }
#undef TILE
#undef STAGE

  // ---- combine group partials via LDS (staging regions are free now) ----
  float* cmb = (float*)(SMEM + 32768);  // 32 KB: [wq][qs][dt][l15][g*4+j]
  float* cl = (float*)SMEM;             // 128 floats: [wq][qs][l15]
  if (grp == 1) {
#pragma unroll
    for (int dt = 0; dt < 4; dt++)
#pragma unroll
      for (int qs = 0; qs < 2; qs++)
        *(f32x4*)&cmb[((((wq * 2 + qs) * 4 + dt) * 16 + l15) * 16) + g * 4] = o[dt][qs];
    if (g == 0) {
      cl[(wq * 2 + 0) * 16 + l15] = ol0[0];
      cl[(wq * 2 + 1) * 16 + l15] = ol1[0];
    }
  }
  asm volatile("s_waitcnt lgkmcnt(0)\n\ts_barrier" ::: "memory");
  if (grp == 0) {
#pragma unroll
    for (int dt = 0; dt < 4; dt++)
#pragma unroll
      for (int qs = 0; qs < 2; qs++)
        o[dt][qs] += *(const f32x4*)&cmb[((((wq * 2 + qs) * 4 + dt) * 16 + l15) * 16) + g * 4];
    float inv0 = 1.0f / (ol0[0] + cl[(wq * 2 + 0) * 16 + l15]);
    float inv1 = 1.0f / (ol1[0] + cl[(wq * 2 + 1) * 16 + l15]);
    int b = bh >> 4, h = bh & 15;
    uint16_t* cr0 = ctx + (size_t)(b * SEQ + q0 + l15) * DM + h * HD + 4 * g;
    uint16_t* cr1 = cr0 + (size_t)16 * DM;
#pragma unroll
    for (int dt = 0; dt < 4; dt++) {
      u32x2 wv;
      wv[0] = cvtpk(o[dt][0][0] * inv0, o[dt][0][1] * inv0);
      wv[1] = cvtpk(o[dt][0][2] * inv0, o[dt][0][3] * inv0);
      *(u32x2*)&cr0[dt * 16] = wv;
      u32x2 wv2;
      wv2[0] = cvtpk(o[dt][1][0] * inv1, o[dt][1][1] * inv1);
      wv2[1] = cvtpk(o[dt][1][2] * inv1, o[dt][1][3] * inv1);
      *(u32x2*)&cr1[dt * 16] = wv2;
    }
  }
}

extern "C" void kernel_launch(void* const* d_in, const int* in_sizes, int n_in,
                              void* d_out, int out_size, void* d_ws, size_t ws_size,
                              hipStream_t stream) {
  const float* x  = (const float*)d_in[0];
  const float* Wq = (const float*)d_in[1];
  const float* bq = (const float*)d_in[2];
  const float* Wk = (const float*)d_in[3];
  const float* bk = (const float*)d_in[4];
  const float* Wv = (const float*)d_in[5];
  const float* bv = (const float*)d_in[6];
  const float* Wo = (const float*)d_in[7];
  const float* bo = (const float*)d_in[8];

  char* ws = (char*)d_ws;
  uint16_t* xb  = (uint16_t*)(ws);               // 8 MB (aliased as ctx later)
  uint16_t* wtq = (uint16_t*)(ws + 8388608);     // 2 MB each
  uint16_t* wtk = (uint16_t*)(ws + 10485760);
  uint16_t* wtv = (uint16_t*)(ws + 12582912);
  uint16_t* wto = (uint16_t*)(ws + 14680064);
  uint16_t* qb  = (uint16_t*)(ws + 16777216);    // 8 MB
  uint16_t* kb  = (uint16_t*)(ws + 25165824);    // 8 MB
  uint16_t* vtb = (uint16_t*)(ws + 33554432);    // 8 MB
  uint16_t* ctx = xb;  // xb dead after gemm_qkv; reuse for ctx

  prep_kernel<<<dim3(8192), dim3(256), 0, stream>>>(
      x, xb, Wq, Wk, Wv, Wo, wtq, wtk, wtv, wto);
  gemm_qkv_kernel<<<dim3(768), dim3(256), 0, stream>>>(
      xb, wtq, wtk, wtv, bq, bk, bv, qb, kb, vtb);
  attn_kernel<<<dim3(512), dim3(512), 0, stream>>>(qb, kb, vtb, ctx);
  gemm_out_kernel<<<dim3(512), dim3(256), 0, stream>>>(ctx, wto, bo, (float*)d_out);
}

// Round 14
// 96.529 us; speedup vs baseline: 2.2219x; 2.2219x over previous
//
#include <hip/hip_runtime.h>
#include <stdint.h>

#define DM 1024
#define SEQ 2048
#define NTOK 4096
#define HD 64

typedef __bf16 bf16x8 __attribute__((ext_vector_type(8)));
typedef float f32x4 __attribute__((ext_vector_type(4)));
typedef uint32_t u32x2 __attribute__((ext_vector_type(2)));
typedef uint32_t u32x4 __attribute__((ext_vector_type(4)));

#if __has_builtin(__builtin_amdgcn_exp2f)
#define EXP2F(x) __builtin_amdgcn_exp2f(x)
#else
#define EXP2F(x) exp2f(x)
#endif

// wave-staging 16B load: global -> LDS (wave-uniform base + lane*16).
// Host pass / no-builtin fallback keeps the source parseable everywhere.
__device__ __forceinline__ void gll16f(const char* g, char* lds_wave_base, int lane) {
#if __has_builtin(__builtin_amdgcn_global_load_lds)
  __builtin_amdgcn_global_load_lds(
      (const __attribute__((address_space(1))) void*)g,
      (__attribute__((address_space(3))) void*)lds_wave_base, 16, 0, 0);
#else
  *(bf16x8*)(lds_wave_base + lane * 16) = *(const bf16x8*)g;
#endif
}

__device__ __forceinline__ uint16_t f2bf(float f) {
  uint32_t x = __float_as_uint(f);
  return (uint16_t)((x + 0x7fffu + ((x >> 16) & 1u)) >> 16);
}

// packed f32 pair -> 2x bf16 dword (lo = a, hi = b)
__device__ __forceinline__ uint32_t cvtpk(float a, float b) {
  uint32_t r;
  asm("v_cvt_pk_bf16_f32 %0, %1, %2" : "=v"(r) : "v"(a), "v"(b));
  return r;
}

__device__ __forceinline__ bf16x8 mk8(uint32_t a, uint32_t b, uint32_t c, uint32_t d) {
  u32x4 t = {a, b, c, d};
  return __builtin_bit_cast(bf16x8, t);
}

// ---------------- prep: x->bf16 (blocks 0..4095) + 4x W transpose ------------
__global__ void prep_kernel(const float* __restrict__ x, uint16_t* __restrict__ xb,
                            const float* __restrict__ W0, const float* __restrict__ W1,
                            const float* __restrict__ W2, const float* __restrict__ W3,
                            uint16_t* __restrict__ T0, uint16_t* __restrict__ T1,
                            uint16_t* __restrict__ T2, uint16_t* __restrict__ T3) {
  __shared__ float t[32][33];
  int bid = blockIdx.x;
  if (bid < 4096) {
    int i = (bid * 256 + threadIdx.x) * 4;
    float4 v = *(const float4*)&x[i];
    uint64_t pk = (uint64_t)f2bf(v.x) | ((uint64_t)f2bf(v.y) << 16) |
                  ((uint64_t)f2bf(v.z) << 32) | ((uint64_t)f2bf(v.w) << 48);
    *(uint64_t*)&xb[i] = pk;
    return;
  }
  int b2 = bid - 4096;
  int zz = b2 >> 10, rr = b2 & 1023;
  const float* W = (zz == 0) ? W0 : (zz == 1) ? W1 : (zz == 2) ? W2 : W3;
  uint16_t* T = (zz == 0) ? T0 : (zz == 1) ? T1 : (zz == 2) ? T2 : T3;
  int tx = threadIdx.x & 31, ty = threadIdx.x >> 5;
  int nb = (rr & 31) * 32, kb = (rr >> 5) * 32;
#pragma unroll
  for (int i = 0; i < 4; i++)
    t[ty + i * 8][tx] = W[(kb + ty + i * 8) * DM + nb + tx];
  __syncthreads();
#pragma unroll
  for (int i = 0; i < 4; i++)
    T[(nb + ty + i * 8) * DM + kb + tx] = f2bf(t[tx][ty + i * 8]);
}

// ---------------- GEMM body: C[4096, 128-col tile] = A @ Bt^T + bias ---------
// Tile = (MF*32) rows x 128 cols, BK=64, 4 waves as 2x2, wave tile (MF*16)x64.
// LDS rows are 128B -> frag reads XOR-swizzled (byte ^ (row&7)<<4), GLL source
// pre-swizzled to match (both-sides rule).
// MODE 0: out bf16 [bh][s][64] scaled   MODE 1: out bf16 [bh][d][s-mu'] (v'')
// MODE 2: out fp32 [row][col]
template <int MODE, int MF>
__device__ __forceinline__ void gemm_body(const uint16_t* __restrict__ A,
                                          const uint16_t* __restrict__ Bt,
                                          const float* __restrict__ bias, float scale,
                                          void* __restrict__ out, uint16_t* lds,
                                          int bx, int by) {
  const int tid = threadIdx.x;
  const int w = tid >> 6, lane = tid & 63;
  const int wr = w >> 1, wc = w & 1;
  const int a15 = lane & 15, a4 = lane >> 4;
  const int m0 = by * (MF * 32), n0 = bx * 128;
  char* lgA = (char*)lds;                 // MF*32 rows x 128B
  char* lgB = (char*)(lds + MF * 2048);   // 128 rows x 128B
  f32x4 acc[MF][4];
#pragma unroll
  for (int m = 0; m < MF; m++)
#pragma unroll
    for (int n = 0; n < 4; n++) acc[m][n] = (f32x4){0.f, 0.f, 0.f, 0.f};

  const char* Ag = (const char*)(A + (size_t)m0 * DM);
  const char* Bg = (const char*)(Bt + (size_t)n0 * DM);
  const int srow = lane >> 3;                        // row-within-8 for staging
  const int scol = ((lane & 7) * 16) ^ (srow << 4);  // pre-swizzled source col
  const int swz = (a15 & 7) << 4;                    // read-side XOR

  for (int k0 = 0; k0 < DM; k0 += 64) {
#pragma unroll
    for (int c = 0; c < MF; c++) {
      int ro = w * (MF * 8) + c * 8 + srow;
      gll16f(Ag + (size_t)ro * (DM * 2) + k0 * 2 + scol, lgA + (w * MF + c) * 1024, lane);
    }
#pragma unroll
    for (int c = 0; c < 4; c++) {
      int ro = w * 32 + c * 8 + srow;
      gll16f(Bg + (size_t)ro * (DM * 2) + k0 * 2 + scol, lgB + (w * 4 + c) * 1024, lane);
    }
    __syncthreads();
    bf16x8 af[MF][2], bfr[4][2];
#pragma unroll
    for (int m = 0; m < MF; m++)
#pragma unroll
      for (int kk = 0; kk < 2; kk++)
        af[m][kk] = *(const bf16x8*)(lgA + (wr * (MF * 16) + m * 16 + a15) * 128 +
                                     ((kk * 64 + a4 * 16) ^ swz));
#pragma unroll
    for (int n = 0; n < 4; n++)
#pragma unroll
      for (int kk = 0; kk < 2; kk++)
        bfr[n][kk] = *(const bf16x8*)(lgB + (wc * 64 + n * 16 + a15) * 128 +
                                      ((kk * 64 + a4 * 16) ^ swz));
#pragma unroll
    for (int kk = 0; kk < 2; kk++)
#pragma unroll
      for (int m = 0; m < MF; m++)
#pragma unroll
        for (int n = 0; n < 4; n++)
          acc[m][n] = __builtin_amdgcn_mfma_f32_16x16x32_bf16(af[m][kk], bfr[n][kk],
                                                              acc[m][n], 0, 0, 0);
    __syncthreads();
  }

#pragma unroll
  for (int m = 0; m < MF; m++) {
#pragma unroll
    for (int n = 0; n < 4; n++) {
      int gr0 = m0 + wr * (MF * 16) + m * 16 + a4 * 4;
      int col = n0 + wc * 64 + n * 16 + a15;
      float bv = bias[col];
      if constexpr (MODE == 2) {
        float* O = (float*)out;
#pragma unroll
        for (int j = 0; j < 4; j++)
          O[(size_t)(gr0 + j) * DM + col] = acc[m][n][j] + bv;
      } else if constexpr (MODE == 0) {
        uint16_t* O = (uint16_t*)out;
        int h = col >> 6, d = col & 63;
#pragma unroll
        for (int j = 0; j < 4; j++) {
          int gr = gr0 + j;
          int b = gr >> 11, s = gr & 2047;
          O[((size_t)(((b << 4) + h)) * SEQ + s) * HD + d] = f2bf((acc[m][n][j] + bv) * scale);
        }
      } else {
        // V'' layout: [bh][d][2048], within each 64-key group keys permuted:
        // pos = kb*32 + g*8 + ehi*4 + j  holds key k = kb*32 + 16*ehi + 4g + j
        uint16_t* O = (uint16_t*)out;
        int h = col >> 6, d = col & 63;
        int b = gr0 >> 11, s0 = gr0 & 2047;
        int it = s0 >> 6, s6 = s0 & 63;
        int pos = (s6 >> 5) * 32 + ((s6 >> 2) & 3) * 8 + ((s6 >> 4) & 1) * 4;
        uint64_t pk = 0;
#pragma unroll
        for (int j = 0; j < 4; j++)
          pk |= (uint64_t)f2bf(acc[m][n][j] + bv) << (16 * j);
        *(uint64_t*)&O[((size_t)(((b << 4) + h)) * HD + d) * SEQ + it * 64 + pos] = pk;
      }
    }
  }
}

#define CS_SCALE 0.180336880f  // log2(e)/sqrt(hd) folded into q

// flat grid 768, XCD-chunked: each XCD gets 96 consecutive (z,y,x) blocks
__global__ __launch_bounds__(256, 2) void gemm_qkv_kernel(
    const uint16_t* __restrict__ xb, const uint16_t* __restrict__ wtq,
    const uint16_t* __restrict__ wtk, const uint16_t* __restrict__ wtv,
    const float* __restrict__ bq, const float* __restrict__ bk,
    const float* __restrict__ bv, uint16_t* __restrict__ qo,
    uint16_t* __restrict__ ko, uint16_t* __restrict__ vto) {
  __shared__ __attribute__((aligned(16))) uint16_t lds[16384];  // 32 KB
  int id = blockIdx.x;
  int swz = (id & 7) * 96 + (id >> 3);
  int z = swz >> 8, r = swz & 255;
  int by = r >> 3, bx = r & 7;
  if (z == 0)      gemm_body<0, 4>(xb, wtq, bq, CS_SCALE, qo, lds, bx, by);
  else if (z == 1) gemm_body<0, 4>(xb, wtk, bk, 1.0f, ko, lds, bx, by);
  else             gemm_body<1, 4>(xb, wtv, bv, 1.0f, vto, lds, bx, by);
}

// flat grid 512, XCD-chunked (64 blocks per XCD)
__global__ __launch_bounds__(256, 2) void gemm_out_kernel(
    const uint16_t* __restrict__ ctx, const uint16_t* __restrict__ wto,
    const float* __restrict__ bo, float* __restrict__ out) {
  __shared__ __attribute__((aligned(16))) uint16_t lds[12288];  // 24 KB
  int id = blockIdx.x;
  int swz = (id & 7) * 64 + (id >> 3);
  int by = swz >> 3, bx = swz & 7;
  gemm_body<2, 2>(ctx, wto, bo, 1.0f, out, lds, bx, by);
}

// ---------------- attention (8 waves: 2 K-groups x 4 q-waves, LDS combine) ---
// q (pre-scaled by CS), k: [bh][s][64]   v'': [bh][d][2048 mu'-permuted]
// 512 blocks x 512 threads. launch_bounds(512,2): VGPR cap 256 (body needs
// ~100-125) -> if allocator lands <=128 VGPR, HW occupancy = 2 blocks/CU =
// 16 waves/CU = 4 waves/SIMD. (512,4) capped VGPR at 64 and spilled -- r13.
// Group g handles keys g*1024..+1023 (16 tiles), own dbuf staging region;
// fixed-scale exp2 softmax => partials combine linearly via LDS at the end.
__global__ __launch_bounds__(512, 2) void attn_kernel(
    const uint16_t* __restrict__ qg, const uint16_t* __restrict__ kg,
    const uint16_t* __restrict__ vtg, uint16_t* __restrict__ ctx) {
  const int tid = threadIdx.x;
  const int w = tid >> 6, l = tid & 63;
  const int grp = w >> 2, wq = w & 3;
  const int l15 = l & 15, g = l >> 4;
  // XCD swizzle: 64 consecutive wg per XCD -> 4 bh per XCD (KV fits L2)
  int id = blockIdx.x;
  int wg = (id & 7) * 64 + (id >> 3);
  int bh = wg >> 4, qb = wg & 15;
  const int q0 = qb * 128 + wq * 32;
  const int kbase = grp * 16;  // this group's first tile (of 32 total)
  const uint16_t* Qb = qg + (size_t)bh * SEQ * HD;
  const char* Kc = (const char*)(kg + (size_t)bh * SEQ * HD);
  const char* Vc = (const char*)(vtg + (size_t)bh * HD * SEQ);

  // [grp][buf][ K 8KB | V 8KB ] = 64 KB; reused as combine buffer at the end
  __shared__ __attribute__((aligned(16))) char SMEM[65536];
  char* Kr0 = SMEM + grp * 32768;            // buf 0 K
  // buf b: K at Kr0 + b*16384, V at Kr0 + b*16384 + 8192

  // staging: 64 rows x 128B per tile; wave wq covers rows wq*16 + i*8 .. +8
  const int srow = l >> 3;                          // 0..7 (row&7 == srow)
  const int scolx = ((l & 7) * 16) ^ (srow << 4);   // swizzled source col

#define STAGE(BUF, IT)                                                         \
  {                                                                            \
    const int it1_ = (IT);                                                     \
    _Pragma("unroll") for (int i = 0; i < 2; i++) {                            \
      int r = wq * 16 + i * 8 + srow;                                          \
      gll16f(Kc + (size_t)(it1_ * 64 + r) * 128 + scolx,                       \
             Kr0 + (BUF) * 16384 + wq * 2048 + i * 1024, l);                   \
      gll16f(Vc + (size_t)r * (SEQ * 2) + it1_ * 128 + scolx,                  \
             Kr0 + (BUF) * 16384 + 8192 + wq * 2048 + i * 1024, l);            \
    }                                                                          \
  }

  // Q B-frags (hoisted): bq[qs][ks] slot(g,e) = Q[q0+qs*16+l15][ks*32+g*8+e]
  bf16x8 bq[2][2];
#pragma unroll
  for (int qs = 0; qs < 2; qs++)
#pragma unroll
    for (int ks = 0; ks < 2; ks++)
      bq[qs][ks] = *(const bf16x8*)&Qb[(size_t)(q0 + qs * 16 + l15) * HD + ks * 32 + g * 8];

  f32x4 o[4][2];  // [dt][qs]
#pragma unroll
  for (int dt = 0; dt < 4; dt++)
#pragma unroll
    for (int qs = 0; qs < 2; qs++) o[dt][qs] = (f32x4){0.f, 0.f, 0.f, 0.f};
  f32x4 ol0 = {0.f, 0.f, 0.f, 0.f}, ol1 = {0.f, 0.f, 0.f, 0.f};  // denominators
  const int swz = (l15 & 7) << 4;               // read-side XOR
  const uint32_t ONE2 = 0x3F803F80u;            // 2x bf16 1.0
  const bf16x8 aones = mk8(ONE2, ONE2, ONE2, ONE2);

#define TILE(ITL, BI, BN)                                                      \
  {                                                                            \
    const int itl_ = (ITL);                                                    \
    if (itl_ + 1 < 16) {                                                       \
      STAGE(BN, kbase + itl_ + 1);                                             \
      asm volatile("s_waitcnt vmcnt(4)\n\ts_barrier" ::: "memory");            \
    } else {                                                                   \
      asm volatile("s_waitcnt vmcnt(0)\n\ts_barrier" ::: "memory");            \
    }                                                                          \
    const char* Kb_ = Kr0 + (BI) * 16384;                                      \
    const char* Vb_ = Kb_ + 8192;                                              \
    /* K A-frags from LDS (swizzled) */                                        \
    bf16x8 ak[4][2];                                                           \
    _Pragma("unroll") for (int kt = 0; kt < 4; kt++)                           \
        _Pragma("unroll") for (int ks = 0; ks < 2; ks++)                       \
            ak[kt][ks] = *(const bf16x8*)&Kb_[(kt * 16 + l15) * 128 +          \
                                              ((ks * 64 + g * 16) ^ swz)];     \
    /* V A-frags (mu' baked into V''): single b128 per frag */                 \
    bf16x8 av[4][2];                                                           \
    _Pragma("unroll") for (int dt = 0; dt < 4; dt++)                           \
        _Pragma("unroll") for (int kb = 0; kb < 2; kb++)                       \
            av[dt][kb] = *(const bf16x8*)&Vb_[(dt * 16 + l15) * 128 +          \
                                              ((kb * 64 + g * 16) ^ swz)];     \
    /* S^T[k][q] (q pre-scaled by CS) */                                       \
    f32x4 s[2][4];                                                             \
    _Pragma("unroll") for (int qs = 0; qs < 2; qs++)                           \
        _Pragma("unroll") for (int kt = 0; kt < 4; kt++)                       \
            s[qs][kt] = (f32x4){0.f, 0.f, 0.f, 0.f};                           \
    __builtin_amdgcn_s_setprio(1);                                             \
    _Pragma("unroll") for (int kt = 0; kt < 4; kt++)                           \
        _Pragma("unroll") for (int ks = 0; ks < 2; ks++) {                     \
      s[0][kt] = __builtin_amdgcn_mfma_f32_16x16x32_bf16(ak[kt][ks], bq[0][ks], s[0][kt], 0, 0, 0); \
      s[1][kt] = __builtin_amdgcn_mfma_f32_16x16x32_bf16(ak[kt][ks], bq[1][ks], s[1][kt], 0, 0, 0); \
    }                                                                          \
    __builtin_amdgcn_s_setprio(0);                                             \
    /* P = exp2(s); pack B-frags via mu' (no fma, no max, no cross-lane) */    \
    float p0[4][4], p1[4][4];                                                  \
    _Pragma("unroll") for (int kt = 0; kt < 4; kt++)                           \
        _Pragma("unroll") for (int j = 0; j < 4; j++) {                        \
      p0[kt][j] = EXP2F(s[0][kt][j]);                                          \
      p1[kt][j] = EXP2F(s[1][kt][j]);                                          \
    }                                                                          \
    bf16x8 bp0[2], bp1[2];                                                     \
    _Pragma("unroll") for (int kb = 0; kb < 2; kb++) {                         \
      bp0[kb] = mk8(cvtpk(p0[2 * kb][0], p0[2 * kb][1]),                       \
                    cvtpk(p0[2 * kb][2], p0[2 * kb][3]),                       \
                    cvtpk(p0[2 * kb + 1][0], p0[2 * kb + 1][1]),               \
                    cvtpk(p0[2 * kb + 1][2], p0[2 * kb + 1][3]));              \
      bp1[kb] = mk8(cvtpk(p1[2 * kb][0], p1[2 * kb][1]),                       \
                    cvtpk(p1[2 * kb][2], p1[2 * kb][3]),                       \
                    cvtpk(p1[2 * kb + 1][0], p1[2 * kb + 1][1]),               \
                    cvtpk(p1[2 * kb + 1][2], p1[2 * kb + 1][3]));              \
    }                                                                          \
    /* O^T += V . P ; l += 1 . P */                                            \
    __builtin_amdgcn_s_setprio(1);                                             \
    _Pragma("unroll") for (int dt = 0; dt < 4; dt++)                           \
        _Pragma("unroll") for (int kb = 0; kb < 2; kb++) {                     \
      o[dt][0] = __builtin_amdgcn_mfma_f32_16x16x32_bf16(av[dt][kb], bp0[kb], o[dt][0], 0, 0, 0); \
      o[dt][1] = __builtin_amdgcn_mfma_f32_16x16x32_bf16(av[dt][kb], bp1[kb], o[dt][1], 0, 0, 0); \
    }                                                                          \
    _Pragma("unroll") for (int kb = 0; kb < 2; kb++) {                         \
      ol0 = __builtin_amdgcn_mfma_f32_16x16x32_bf16(aones, bp0[kb], ol0, 0, 0, 0); \
      ol1 = __builtin_amdgcn_mfma_f32_16x16x32_bf16(aones, bp1[kb], ol1, 0, 0, 0); \
    }                                                                          \
    __builtin_amdgcn_s_setprio(0);                                             \
    asm volatile("s_waitcnt lgkmcnt(0)\n\ts_barrier" ::: "memory");            \
  }

  // prologue: stage this group's first tile into buf 0
  STAGE(0, kbase);
  asm volatile("s_waitcnt vmcnt(0)\n\ts_barrier" ::: "memory");

  for (int it2 = 0; it2 < 8; ++it2) {
    TILE(2 * it2, 0, 1);
    TILE(2 * it2 + 1, 1, 0);
  }
#undef TILE
#undef STAGE

  // ---- combine group partials via LDS (staging regions are free now) ----
  float* cmb = (float*)(SMEM + 32768);  // 32 KB: [wq][qs][dt][l15][g*4+j]
  float* cl = (float*)SMEM;             // 128 floats: [wq][qs][l15]
  if (grp == 1) {
#pragma unroll
    for (int dt = 0; dt < 4; dt++)
#pragma unroll
      for (int qs = 0; qs < 2; qs++)
        *(f32x4*)&cmb[((((wq * 2 + qs) * 4 + dt) * 16 + l15) * 16) + g * 4] = o[dt][qs];
    if (g == 0) {
      cl[(wq * 2 + 0) * 16 + l15] = ol0[0];
      cl[(wq * 2 + 1) * 16 + l15] = ol1[0];
    }
  }
  asm volatile("s_waitcnt lgkmcnt(0)\n\ts_barrier" ::: "memory");
  if (grp == 0) {
#pragma unroll
    for (int dt = 0; dt < 4; dt++)
#pragma unroll
      for (int qs = 0; qs < 2; qs++)
        o[dt][qs] += *(const f32x4*)&cmb[((((wq * 2 + qs) * 4 + dt) * 16 + l15) * 16) + g * 4];
    float inv0 = 1.0f / (ol0[0] + cl[(wq * 2 + 0) * 16 + l15]);
    float inv1 = 1.0f / (ol1[0] + cl[(wq * 2 + 1) * 16 + l15]);
    int b = bh >> 4, h = bh & 15;
    uint16_t* cr0 = ctx + (size_t)(b * SEQ + q0 + l15) * DM + h * HD + 4 * g;
    uint16_t* cr1 = cr0 + (size_t)16 * DM;
#pragma unroll
    for (int dt = 0; dt < 4; dt++) {
      u32x2 wv;
      wv[0] = cvtpk(o[dt][0][0] * inv0, o[dt][0][1] * inv0);
      wv[1] = cvtpk(o[dt][0][2] * inv0, o[dt][0][3] * inv0);
      *(u32x2*)&cr0[dt * 16] = wv;
      u32x2 wv2;
      wv2[0] = cvtpk(o[dt][1][0] * inv1, o[dt][1][1] * inv1);
      wv2[1] = cvtpk(o[dt][1][2] * inv1, o[dt][1][3] * inv1);
      *(u32x2*)&cr1[dt * 16] = wv2;
    }
  }
}

extern "C" void kernel_launch(void* const* d_in, const int* in_sizes, int n_in,
                              void* d_out, int out_size, void* d_ws, size_t ws_size,
                              hipStream_t stream) {
  const float* x  = (const float*)d_in[0];
  const float* Wq = (const float*)d_in[1];
  const float* bq = (const float*)d_in[2];
  const float* Wk = (const float*)d_in[3];
  const float* bk = (const float*)d_in[4];
  const float* Wv = (const float*)d_in[5];
  const float* bv = (const float*)d_in[6];
  const float* Wo = (const float*)d_in[7];
  const float* bo = (const float*)d_in[8];

  char* ws = (char*)d_ws;
  uint16_t* xb  = (uint16_t*)(ws);               // 8 MB (aliased as ctx later)
  uint16_t* wtq = (uint16_t*)(ws + 8388608);     // 2 MB each
  uint16_t* wtk = (uint16_t*)(ws + 10485760);
  uint16_t* wtv = (uint16_t*)(ws + 12582912);
  uint16_t* wto = (uint16_t*)(ws + 14680064);
  uint16_t* qb  = (uint16_t*)(ws + 16777216);    // 8 MB
  uint16_t* kb  = (uint16_t*)(ws + 25165824);    // 8 MB
  uint16_t* vtb = (uint16_t*)(ws + 33554432);    // 8 MB
  uint16_t* ctx = xb;  // xb dead after gemm_qkv; reuse for ctx

  prep_kernel<<<dim3(8192), dim3(256), 0, stream>>>(
      x, xb, Wq, Wk, Wv, Wo, wtq, wtk, wtv, wto);
  gemm_qkv_kernel<<<dim3(768), dim3(256), 0, stream>>>(
      xb, wtq, wtk, wtv, bq, bk, bv, qb, kb, vtb);
  attn_kernel<<<dim3(512), dim3(512), 0, stream>>>(qb, kb, vtb, ctx);
  gemm_out_kernel<<<dim3(512), dim3(256), 0, stream>>>(ctx, wto, bo, (float*)d_out);
}

// Round 15
// 95.694 us; speedup vs baseline: 2.2413x; 1.0087x over previous
//
#include <hip/hip_runtime.h>
#include <stdint.h>

#define DM 1024
#define SEQ 2048
#define NTOK 4096
#define HD 64

typedef __bf16 bf16x8 __attribute__((ext_vector_type(8)));
typedef float f32x4 __attribute__((ext_vector_type(4)));
typedef uint32_t u32x2 __attribute__((ext_vector_type(2)));
typedef uint32_t u32x4 __attribute__((ext_vector_type(4)));

#if __has_builtin(__builtin_amdgcn_exp2f)
#define EXP2F(x) __builtin_amdgcn_exp2f(x)
#else
#define EXP2F(x) exp2f(x)
#endif

// wave-staging 16B load: global -> LDS (wave-uniform base + lane*16).
// Host pass / no-builtin fallback keeps the source parseable everywhere.
__device__ __forceinline__ void gll16f(const char* g, char* lds_wave_base, int lane) {
#if __has_builtin(__builtin_amdgcn_global_load_lds)
  __builtin_amdgcn_global_load_lds(
      (const __attribute__((address_space(1))) void*)g,
      (__attribute__((address_space(3))) void*)lds_wave_base, 16, 0, 0);
#else
  *(bf16x8*)(lds_wave_base + lane * 16) = *(const bf16x8*)g;
#endif
}

__device__ __forceinline__ uint16_t f2bf(float f) {
  uint32_t x = __float_as_uint(f);
  return (uint16_t)((x + 0x7fffu + ((x >> 16) & 1u)) >> 16);
}

// packed f32 pair -> 2x bf16 dword (lo = a, hi = b)
__device__ __forceinline__ uint32_t cvtpk(float a, float b) {
  uint32_t r;
  asm("v_cvt_pk_bf16_f32 %0, %1, %2" : "=v"(r) : "v"(a), "v"(b));
  return r;
}

__device__ __forceinline__ bf16x8 mk8(uint32_t a, uint32_t b, uint32_t c, uint32_t d) {
  u32x4 t = {a, b, c, d};
  return __builtin_bit_cast(bf16x8, t);
}

// ---------------- prep: x->bf16 (blocks 0..4095) + 4x W transpose ------------
__global__ void prep_kernel(const float* __restrict__ x, uint16_t* __restrict__ xb,
                            const float* __restrict__ W0, const float* __restrict__ W1,
                            const float* __restrict__ W2, const float* __restrict__ W3,
                            uint16_t* __restrict__ T0, uint16_t* __restrict__ T1,
                            uint16_t* __restrict__ T2, uint16_t* __restrict__ T3) {
  __shared__ float t[32][33];
  int bid = blockIdx.x;
  if (bid < 4096) {
    int i = (bid * 256 + threadIdx.x) * 4;
    float4 v = *(const float4*)&x[i];
    uint64_t pk = (uint64_t)f2bf(v.x) | ((uint64_t)f2bf(v.y) << 16) |
                  ((uint64_t)f2bf(v.z) << 32) | ((uint64_t)f2bf(v.w) << 48);
    *(uint64_t*)&xb[i] = pk;
    return;
  }
  int b2 = bid - 4096;
  int zz = b2 >> 10, rr = b2 & 1023;
  const float* W = (zz == 0) ? W0 : (zz == 1) ? W1 : (zz == 2) ? W2 : W3;
  uint16_t* T = (zz == 0) ? T0 : (zz == 1) ? T1 : (zz == 2) ? T2 : T3;
  int tx = threadIdx.x & 31, ty = threadIdx.x >> 5;
  int nb = (rr & 31) * 32, kb = (rr >> 5) * 32;
#pragma unroll
  for (int i = 0; i < 4; i++)
    t[ty + i * 8][tx] = W[(kb + ty + i * 8) * DM + nb + tx];
  __syncthreads();
#pragma unroll
  for (int i = 0; i < 4; i++)
    T[(nb + ty + i * 8) * DM + kb + tx] = f2bf(t[tx][ty + i * 8]);
}

// ---------------- GEMM body: C[4096, 128-col tile] = A @ Bt^T + bias ---------
// Tile = (MF*32) rows x 128 cols, BK=64, 4 waves as 2x2, wave tile (MF*16)x64.
// LDS rows are 128B -> frag reads XOR-swizzled (byte ^ (row&7)<<4), GLL source
// pre-swizzled to match (both-sides rule).
// MODE 0: out bf16 [bh][s][64] scaled   MODE 1: out bf16 V''' fragment-major
// MODE 2: out fp32 [row][col]
template <int MODE, int MF>
__device__ __forceinline__ void gemm_body(const uint16_t* __restrict__ A,
                                          const uint16_t* __restrict__ Bt,
                                          const float* __restrict__ bias, float scale,
                                          void* __restrict__ out, uint16_t* lds,
                                          int bx, int by) {
  const int tid = threadIdx.x;
  const int w = tid >> 6, lane = tid & 63;
  const int wr = w >> 1, wc = w & 1;
  const int a15 = lane & 15, a4 = lane >> 4;
  const int m0 = by * (MF * 32), n0 = bx * 128;
  char* lgA = (char*)lds;                 // MF*32 rows x 128B
  char* lgB = (char*)(lds + MF * 2048);   // 128 rows x 128B
  f32x4 acc[MF][4];
#pragma unroll
  for (int m = 0; m < MF; m++)
#pragma unroll
    for (int n = 0; n < 4; n++) acc[m][n] = (f32x4){0.f, 0.f, 0.f, 0.f};

  const char* Ag = (const char*)(A + (size_t)m0 * DM);
  const char* Bg = (const char*)(Bt + (size_t)n0 * DM);
  const int srow = lane >> 3;                        // row-within-8 for staging
  const int scol = ((lane & 7) * 16) ^ (srow << 4);  // pre-swizzled source col
  const int swz = (a15 & 7) << 4;                    // read-side XOR

  for (int k0 = 0; k0 < DM; k0 += 64) {
#pragma unroll
    for (int c = 0; c < MF; c++) {
      int ro = w * (MF * 8) + c * 8 + srow;
      gll16f(Ag + (size_t)ro * (DM * 2) + k0 * 2 + scol, lgA + (w * MF + c) * 1024, lane);
    }
#pragma unroll
    for (int c = 0; c < 4; c++) {
      int ro = w * 32 + c * 8 + srow;
      gll16f(Bg + (size_t)ro * (DM * 2) + k0 * 2 + scol, lgB + (w * 4 + c) * 1024, lane);
    }
    __syncthreads();
    bf16x8 af[MF][2], bfr[4][2];
#pragma unroll
    for (int m = 0; m < MF; m++)
#pragma unroll
      for (int kk = 0; kk < 2; kk++)
        af[m][kk] = *(const bf16x8*)(lgA + (wr * (MF * 16) + m * 16 + a15) * 128 +
                                     ((kk * 64 + a4 * 16) ^ swz));
#pragma unroll
    for (int n = 0; n < 4; n++)
#pragma unroll
      for (int kk = 0; kk < 2; kk++)
        bfr[n][kk] = *(const bf16x8*)(lgB + (wc * 64 + n * 16 + a15) * 128 +
                                      ((kk * 64 + a4 * 16) ^ swz));
#pragma unroll
    for (int kk = 0; kk < 2; kk++)
#pragma unroll
      for (int m = 0; m < MF; m++)
#pragma unroll
        for (int n = 0; n < 4; n++)
          acc[m][n] = __builtin_amdgcn_mfma_f32_16x16x32_bf16(af[m][kk], bfr[n][kk],
                                                              acc[m][n], 0, 0, 0);
    __syncthreads();
  }

#pragma unroll
  for (int m = 0; m < MF; m++) {
#pragma unroll
    for (int n = 0; n < 4; n++) {
      int gr0 = m0 + wr * (MF * 16) + m * 16 + a4 * 4;
      int col = n0 + wc * 64 + n * 16 + a15;
      float bv = bias[col];
      if constexpr (MODE == 2) {
        float* O = (float*)out;
#pragma unroll
        for (int j = 0; j < 4; j++)
          O[(size_t)(gr0 + j) * DM + col] = acc[m][n][j] + bv;
      } else if constexpr (MODE == 0) {
        uint16_t* O = (uint16_t*)out;
        int h = col >> 6, d = col & 63;
#pragma unroll
        for (int j = 0; j < 4; j++) {
          int gr = gr0 + j;
          int b = gr >> 11, s = gr & 2047;
          O[((size_t)(((b << 4) + h)) * SEQ + s) * HD + d] = f2bf((acc[m][n][j] + bv) * scale);
        }
      } else {
        // V''' fragment-major: flat [it][dt][kb][lane][8] per bh (512 elems
        // per (it,dt,kb) group). Element e of lane (g*16+l15) holds
        // v[d=dt*16+l15][k=kb*32+16*(e>>2)+4g+(e&3)]; attn reads one b128 at
        // base + lane*16 (fully coalesced). 4 consecutive s -> 4 consecutive
        // e in one lane -> one 8B store.
        uint16_t* O = (uint16_t*)out;
        int h = col >> 6, d = col & 63;
        int b = gr0 >> 11, s0 = gr0 & 2047;
        int it = s0 >> 6, inner = s0 & 63;
        int kb2 = inner >> 5, r5 = inner & 31;
        int g2 = (r5 >> 2) & 3, ehi = r5 >> 4;
        int dt2 = d >> 4, l15v = d & 15;
        size_t idx = (size_t)(((b << 4) + h)) * (HD * SEQ) +
                     (size_t)(it * 8 + dt2 * 2 + kb2) * 512 +
                     (g2 * 16 + l15v) * 8 + ehi * 4;
        uint64_t pk = 0;
#pragma unroll
        for (int j = 0; j < 4; j++)
          pk |= (uint64_t)f2bf(acc[m][n][j] + bv) << (16 * j);
        *(uint64_t*)&O[idx] = pk;
      }
    }
  }
}

#define CS_SCALE 0.180336880f  // log2(e)/sqrt(hd) folded into q

// flat grid 768, XCD-chunked: each XCD gets 96 consecutive (z,y,x) blocks
__global__ __launch_bounds__(256, 2) void gemm_qkv_kernel(
    const uint16_t* __restrict__ xb, const uint16_t* __restrict__ wtq,
    const uint16_t* __restrict__ wtk, const uint16_t* __restrict__ wtv,
    const float* __restrict__ bq, const float* __restrict__ bk,
    const float* __restrict__ bv, uint16_t* __restrict__ qo,
    uint16_t* __restrict__ ko, uint16_t* __restrict__ vto) {
  __shared__ __attribute__((aligned(16))) uint16_t lds[16384];  // 32 KB
  int id = blockIdx.x;
  int swz = (id & 7) * 96 + (id >> 3);
  int z = swz >> 8, r = swz & 255;
  int by = r >> 3, bx = r & 7;
  if (z == 0)      gemm_body<0, 4>(xb, wtq, bq, CS_SCALE, qo, lds, bx, by);
  else if (z == 1) gemm_body<0, 4>(xb, wtk, bk, 1.0f, ko, lds, bx, by);
  else             gemm_body<1, 4>(xb, wtv, bv, 1.0f, vto, lds, bx, by);
}

// flat grid 512, XCD-chunked (64 blocks per XCD)
__global__ __launch_bounds__(256, 2) void gemm_out_kernel(
    const uint16_t* __restrict__ ctx, const uint16_t* __restrict__ wto,
    const float* __restrict__ bo, float* __restrict__ out) {
  __shared__ __attribute__((aligned(16))) uint16_t lds[12288];  // 24 KB
  int id = blockIdx.x;
  int swz = (id & 7) * 64 + (id >> 3);
  int by = swz >> 3, bx = swz & 7;
  gemm_body<2, 2>(ctx, wto, bo, 1.0f, out, lds, bx, by);
}

// ---------------- attention (K via LDS, V''' coalesced reg prefetch) ---------
// q (pre-scaled by CS), k: [bh][s][64]   v''': fragment-major (see producer)
// 512 blocks x 4 waves (128 q/block), 2 blocks/CU. P = exp2(s') directly;
// denominator via ones-MFMA. V frag = b128 at base + lane*16 (coalesced) ->
// prefetched one tile ahead into named reg bufs (avA/avB); K double-buffered
// in LDS via GLL. Per tile/wave: 8 V-loads + 2 K-GLLs = 10 VMEM; counted
// s_waitcnt vmcnt(10) => previous tile's K staged + V regs ready (FIFO).
// LDS port now carries K only (~half traffic); V rides L1/L2 in parallel.
__global__ __launch_bounds__(256, 2) void attn_kernel(
    const uint16_t* __restrict__ qg, const uint16_t* __restrict__ kg,
    const uint16_t* __restrict__ vtg, uint16_t* __restrict__ ctx) {
  const int tid = threadIdx.x;
  const int w = tid >> 6, l = tid & 63;
  const int l15 = l & 15, g = l >> 4;
  // XCD swizzle: 64 consecutive wg per XCD -> 4 bh per XCD (KV fits L2)
  int id = blockIdx.x;
  int wg = (id & 7) * 64 + (id >> 3);
  int bh = wg >> 4, qb = wg & 15;
  const int q0 = qb * 128 + w * 32;
  const uint16_t* Qb = qg + (size_t)bh * SEQ * HD;
  const char* Kc = (const char*)(kg + (size_t)bh * SEQ * HD);
  const uint16_t* Vl = vtg + (size_t)bh * (HD * SEQ) + l * 8;  // per-lane base

  __shared__ __attribute__((aligned(16))) char Klds[2][8192];

  // K staging: 64 rows x 128B per tile; wave w covers rows w*16 + i*8 .. +8
  const int srow = l >> 3;                          // 0..7 (row&7 == srow)
  const int scolx = ((l & 7) * 16) ^ (srow << 4);   // swizzled source col

#define STAGE(BI, IT)                                                          \
  {                                                                            \
    const int it1_ = (IT);                                                     \
    _Pragma("unroll") for (int i = 0; i < 2; i++) {                            \
      int r = w * 16 + i * 8 + srow;                                           \
      gll16f(Kc + (size_t)(it1_ * 64 + r) * 128 + scolx,                       \
             &Klds[BI][w * 2048 + i * 1024], l);                               \
    }                                                                          \
  }

#define VLOAD(AV, IT)                                                          \
  {                                                                            \
    const int itv_ = (IT);                                                     \
    _Pragma("unroll") for (int dt = 0; dt < 4; dt++)                           \
        _Pragma("unroll") for (int kb = 0; kb < 2; kb++)                       \
            AV[dt][kb] = *(const bf16x8*)&Vl[(size_t)(itv_ * 8 + dt * 2 + kb) * 512]; \
  }

  // Q B-frags (hoisted): bq[qs][ks] slot(g,e) = Q[q0+qs*16+l15][ks*32+g*8+e]
  bf16x8 bq[2][2];
#pragma unroll
  for (int qs = 0; qs < 2; qs++)
#pragma unroll
    for (int ks = 0; ks < 2; ks++)
      bq[qs][ks] = *(const bf16x8*)&Qb[(size_t)(q0 + qs * 16 + l15) * HD + ks * 32 + g * 8];

  f32x4 o[4][2];  // [dt][qs]
#pragma unroll
  for (int dt = 0; dt < 4; dt++)
#pragma unroll
    for (int qs = 0; qs < 2; qs++) o[dt][qs] = (f32x4){0.f, 0.f, 0.f, 0.f};
  f32x4 ol0 = {0.f, 0.f, 0.f, 0.f}, ol1 = {0.f, 0.f, 0.f, 0.f};  // denominators
  const int swz = (l15 & 7) << 4;               // read-side XOR
  const uint32_t ONE2 = 0x3F803F80u;            // 2x bf16 1.0
  const bf16x8 aones = mk8(ONE2, ONE2, ONE2, ONE2);

  bf16x8 avA[4][2], avB[4][2];

#define TILE(IT, BI, BN, AVC, AVN)                                             \
  {                                                                            \
    const int it_ = (IT);                                                      \
    if (it_ + 1 < SEQ / 64) {                                                  \
      VLOAD(AVN, it_ + 1);                                                     \
      STAGE(BN, it_ + 1);                                                      \
      asm volatile("s_waitcnt vmcnt(10)\n\ts_barrier" ::: "memory");           \
    } else {                                                                   \
      asm volatile("s_waitcnt vmcnt(0)\n\ts_barrier" ::: "memory");            \
    }                                                                          \
    /* K A-frags from LDS (swizzled) */                                        \
    bf16x8 ak[4][2];                                                           \
    _Pragma("unroll") for (int kt = 0; kt < 4; kt++)                           \
        _Pragma("unroll") for (int ks = 0; ks < 2; ks++)                       \
            ak[kt][ks] = *(const bf16x8*)&Klds[BI][(kt * 16 + l15) * 128 +     \
                                                   ((ks * 64 + g * 16) ^ swz)];\
    /* S^T[k][q] (q pre-scaled by CS) */                                       \
    f32x4 s[2][4];                                                             \
    _Pragma("unroll") for (int qs = 0; qs < 2; qs++)                           \
        _Pragma("unroll") for (int kt = 0; kt < 4; kt++)                       \
            s[qs][kt] = (f32x4){0.f, 0.f, 0.f, 0.f};                           \
    __builtin_amdgcn_s_setprio(1);                                             \
    _Pragma("unroll") for (int kt = 0; kt < 4; kt++)                           \
        _Pragma("unroll") for (int ks = 0; ks < 2; ks++) {                     \
      s[0][kt] = __builtin_amdgcn_mfma_f32_16x16x32_bf16(ak[kt][ks], bq[0][ks], s[0][kt], 0, 0, 0); \
      s[1][kt] = __builtin_amdgcn_mfma_f32_16x16x32_bf16(ak[kt][ks], bq[1][ks], s[1][kt], 0, 0, 0); \
    }                                                                          \
    __builtin_amdgcn_s_setprio(0);                                             \
    /* P = exp2(s); pack B-frags via mu' (no fma, no max, no cross-lane) */    \
    float p0[4][4], p1[4][4];                                                  \
    _Pragma("unroll") for (int kt = 0; kt < 4; kt++)                           \
        _Pragma("unroll") for (int j = 0; j < 4; j++) {                        \
      p0[kt][j] = EXP2F(s[0][kt][j]);                                          \
      p1[kt][j] = EXP2F(s[1][kt][j]);                                          \
    }                                                                          \
    bf16x8 bp0[2], bp1[2];                                                     \
    _Pragma("unroll") for (int kb = 0; kb < 2; kb++) {                         \
      bp0[kb] = mk8(cvtpk(p0[2 * kb][0], p0[2 * kb][1]),                       \
                    cvtpk(p0[2 * kb][2], p0[2 * kb][3]),                       \
                    cvtpk(p0[2 * kb + 1][0], p0[2 * kb + 1][1]),               \
                    cvtpk(p0[2 * kb + 1][2], p0[2 * kb + 1][3]));              \
      bp1[kb] = mk8(cvtpk(p1[2 * kb][0], p1[2 * kb][1]),                       \
                    cvtpk(p1[2 * kb][2], p1[2 * kb][3]),                       \
                    cvtpk(p1[2 * kb + 1][0], p1[2 * kb + 1][1]),               \
                    cvtpk(p1[2 * kb + 1][2], p1[2 * kb + 1][3]));              \
    }                                                                          \
    /* O^T += V . P ; l += 1 . P */                                            \
    __builtin_amdgcn_s_setprio(1);                                             \
    _Pragma("unroll") for (int dt = 0; dt < 4; dt++)                           \
        _Pragma("unroll") for (int kb = 0; kb < 2; kb++) {                     \
      o[dt][0] = __builtin_amdgcn_mfma_f32_16x16x32_bf16(AVC[dt][kb], bp0[kb], o[dt][0], 0, 0, 0); \
      o[dt][1] = __builtin_amdgcn_mfma_f32_16x16x32_bf16(AVC[dt][kb], bp1[kb], o[dt][1], 0, 0, 0); \
    }                                                                          \
    _Pragma("unroll") for (int kb = 0; kb < 2; kb++) {                         \
      ol0 = __builtin_amdgcn_mfma_f32_16x16x32_bf16(aones, bp0[kb], ol0, 0, 0, 0); \
      ol1 = __builtin_amdgcn_mfma_f32_16x16x32_bf16(aones, bp1[kb], ol1, 0, 0, 0); \
    }                                                                          \
    __builtin_amdgcn_s_setprio(0);                                             \
    asm volatile("s_waitcnt lgkmcnt(0)\n\ts_barrier" ::: "memory");            \
  }

  // prologue: V(0) -> avA, K(0) -> slot 0; drain, then barrier
  VLOAD(avA, 0);
  STAGE(0, 0);
  asm volatile("s_waitcnt vmcnt(0)\n\ts_barrier" ::: "memory");

  for (int it2 = 0; it2 < SEQ / 128; ++it2) {
    TILE(2 * it2, 0, 1, avA, avB);
    TILE(2 * it2 + 1, 1, 0, avB, avA);
  }
#undef TILE
#undef VLOAD
#undef STAGE

  float inv0 = 1.0f / ol0[0];
  float inv1 = 1.0f / ol1[0];
  int b = bh >> 4, h = bh & 15;
  uint16_t* cr0 = ctx + (size_t)(b * SEQ + q0 + l15) * DM + h * HD + 4 * g;
  uint16_t* cr1 = cr0 + (size_t)16 * DM;
#pragma unroll
  for (int dt = 0; dt < 4; dt++) {
    u32x2 wv;
    wv[0] = cvtpk(o[dt][0][0] * inv0, o[dt][0][1] * inv0);
    wv[1] = cvtpk(o[dt][0][2] * inv0, o[dt][0][3] * inv0);
    *(u32x2*)&cr0[dt * 16] = wv;
    u32x2 wv2;
    wv2[0] = cvtpk(o[dt][1][0] * inv1, o[dt][1][1] * inv1);
    wv2[1] = cvtpk(o[dt][1][2] * inv1, o[dt][1][3] * inv1);
    *(u32x2*)&cr1[dt * 16] = wv2;
  }
}

extern "C" void kernel_launch(void* const* d_in, const int* in_sizes, int n_in,
                              void* d_out, int out_size, void* d_ws, size_t ws_size,
                              hipStream_t stream) {
  const float* x  = (const float*)d_in[0];
  const float* Wq = (const float*)d_in[1];
  const float* bq = (const float*)d_in[2];
  const float* Wk = (const float*)d_in[3];
  const float* bk = (const float*)d_in[4];
  const float* Wv = (const float*)d_in[5];
  const float* bv = (const float*)d_in[6];
  const float* Wo = (const float*)d_in[7];
  const float* bo = (const float*)d_in[8];

  char* ws = (char*)d_ws;
  uint16_t* xb  = (uint16_t*)(ws);               // 8 MB (aliased as ctx later)
  uint16_t* wtq = (uint16_t*)(ws + 8388608);     // 2 MB each
  uint16_t* wtk = (uint16_t*)(ws + 10485760);
  uint16_t* wtv = (uint16_t*)(ws + 12582912);
  uint16_t* wto = (uint16_t*)(ws + 14680064);
  uint16_t* qb  = (uint16_t*)(ws + 16777216);    // 8 MB
  uint16_t* kb  = (uint16_t*)(ws + 25165824);    // 8 MB
  uint16_t* vtb = (uint16_t*)(ws + 33554432);    // 8 MB
  uint16_t* ctx = xb;  // xb dead after gemm_qkv; reuse for ctx

  prep_kernel<<<dim3(8192), dim3(256), 0, stream>>>(
      x, xb, Wq, Wk, Wv, Wo, wtq, wtk, wtv, wto);
  gemm_qkv_kernel<<<dim3(768), dim3(256), 0, stream>>>(
      xb, wtq, wtk, wtv, bq, bk, bv, qb, kb, vtb);
  attn_kernel<<<dim3(512), dim3(256), 0, stream>>>(qb, kb, vtb, ctx);
  gemm_out_kernel<<<dim3(512), dim3(256), 0, stream>>>(ctx, wto, bo, (float*)d_out);
}

// Round 17
// 92.107 us; speedup vs baseline: 2.3286x; 1.0389x over previous
//
#include <hip/hip_runtime.h>
#include <stdint.h>

#define DM 1024
#define SEQ 2048
#define NTOK 4096
#define HD 64

typedef __bf16 bf16x8 __attribute__((ext_vector_type(8)));
typedef float f32x4 __attribute__((ext_vector_type(4)));
typedef uint32_t u32x2 __attribute__((ext_vector_type(2)));
typedef uint32_t u32x4 __attribute__((ext_vector_type(4)));

#if __has_builtin(__builtin_amdgcn_exp2f)
#define EXP2F(x) __builtin_amdgcn_exp2f(x)
#else
#define EXP2F(x) exp2f(x)
#endif

// wave-staging 16B load: global -> LDS (wave-uniform base + lane*16).
// Host pass / no-builtin fallback keeps the source parseable everywhere.
__device__ __forceinline__ void gll16f(const char* g, char* lds_wave_base, int lane) {
#if __has_builtin(__builtin_amdgcn_global_load_lds)
  __builtin_amdgcn_global_load_lds(
      (const __attribute__((address_space(1))) void*)g,
      (__attribute__((address_space(3))) void*)lds_wave_base, 16, 0, 0);
#else
  *(bf16x8*)(lds_wave_base + lane * 16) = *(const bf16x8*)g;
#endif
}

__device__ __forceinline__ uint16_t f2bf(float f) {
  uint32_t x = __float_as_uint(f);
  return (uint16_t)((x + 0x7fffu + ((x >> 16) & 1u)) >> 16);
}

// packed f32 pair -> 2x bf16 dword (lo = a, hi = b)
__device__ __forceinline__ uint32_t cvtpk(float a, float b) {
  uint32_t r;
  asm("v_cvt_pk_bf16_f32 %0, %1, %2" : "=v"(r) : "v"(a), "v"(b));
  return r;
}

__device__ __forceinline__ bf16x8 mk8(uint32_t a, uint32_t b, uint32_t c, uint32_t d) {
  u32x4 t = {a, b, c, d};
  return __builtin_bit_cast(bf16x8, t);
}

// ---------------- prep: x->bf16 (blocks 0..4095) + 4x W transpose ------------
__global__ void prep_kernel(const float* __restrict__ x, uint16_t* __restrict__ xb,
                            const float* __restrict__ W0, const float* __restrict__ W1,
                            const float* __restrict__ W2, const float* __restrict__ W3,
                            uint16_t* __restrict__ T0, uint16_t* __restrict__ T1,
                            uint16_t* __restrict__ T2, uint16_t* __restrict__ T3) {
  __shared__ float t[32][33];
  int bid = blockIdx.x;
  if (bid < 4096) {
    int i = (bid * 256 + threadIdx.x) * 4;
    float4 v = *(const float4*)&x[i];
    uint64_t pk = (uint64_t)f2bf(v.x) | ((uint64_t)f2bf(v.y) << 16) |
                  ((uint64_t)f2bf(v.z) << 32) | ((uint64_t)f2bf(v.w) << 48);
    *(uint64_t*)&xb[i] = pk;
    return;
  }
  int b2 = bid - 4096;
  int zz = b2 >> 10, rr = b2 & 1023;
  const float* W = (zz == 0) ? W0 : (zz == 1) ? W1 : (zz == 2) ? W2 : W3;
  uint16_t* T = (zz == 0) ? T0 : (zz == 1) ? T1 : (zz == 2) ? T2 : T3;
  int tx = threadIdx.x & 31, ty = threadIdx.x >> 5;
  int nb = (rr & 31) * 32, kb = (rr >> 5) * 32;
#pragma unroll
  for (int i = 0; i < 4; i++)
    t[ty + i * 8][tx] = W[(kb + ty + i * 8) * DM + nb + tx];
  __syncthreads();
#pragma unroll
  for (int i = 0; i < 4; i++)
    T[(nb + ty + i * 8) * DM + kb + tx] = f2bf(t[tx][ty + i * 8]);
}

// ---------------- GEMM body: C[4096, 128-col tile] = A @ Bt^T + bias ---------
// Tile = (MF*32) rows x 128 cols, BK=64, 4 waves as 2x2, wave tile (MF*16)x64.
// LDS rows are 128B -> frag reads XOR-swizzled (byte ^ (row&7)<<4), GLL source
// pre-swizzled to match (both-sides rule).
// MODE 0: out bf16 [bh][s][64] scaled   MODE 1: out bf16 [bh][d][s-mu'] (v'')
// MODE 2: out fp32 [row][col]
template <int MODE, int MF>
__device__ __forceinline__ void gemm_body(const uint16_t* __restrict__ A,
                                          const uint16_t* __restrict__ Bt,
                                          const float* __restrict__ bias, float scale,
                                          void* __restrict__ out, uint16_t* lds,
                                          int bx, int by) {
  const int tid = threadIdx.x;
  const int w = tid >> 6, lane = tid & 63;
  const int wr = w >> 1, wc = w & 1;
  const int a15 = lane & 15, a4 = lane >> 4;
  const int m0 = by * (MF * 32), n0 = bx * 128;
  char* lgA = (char*)lds;                 // MF*32 rows x 128B
  char* lgB = (char*)(lds + MF * 2048);   // 128 rows x 128B
  f32x4 acc[MF][4];
#pragma unroll
  for (int m = 0; m < MF; m++)
#pragma unroll
    for (int n = 0; n < 4; n++) acc[m][n] = (f32x4){0.f, 0.f, 0.f, 0.f};

  const char* Ag = (const char*)(A + (size_t)m0 * DM);
  const char* Bg = (const char*)(Bt + (size_t)n0 * DM);
  const int srow = lane >> 3;                        // row-within-8 for staging
  const int scol = ((lane & 7) * 16) ^ (srow << 4);  // pre-swizzled source col
  const int swz = (a15 & 7) << 4;                    // read-side XOR

  for (int k0 = 0; k0 < DM; k0 += 64) {
#pragma unroll
    for (int c = 0; c < MF; c++) {
      int ro = w * (MF * 8) + c * 8 + srow;
      gll16f(Ag + (size_t)ro * (DM * 2) + k0 * 2 + scol, lgA + (w * MF + c) * 1024, lane);
    }
#pragma unroll
    for (int c = 0; c < 4; c++) {
      int ro = w * 32 + c * 8 + srow;
      gll16f(Bg + (size_t)ro * (DM * 2) + k0 * 2 + scol, lgB + (w * 4 + c) * 1024, lane);
    }
    __syncthreads();
    bf16x8 af[MF][2], bfr[4][2];
#pragma unroll
    for (int m = 0; m < MF; m++)
#pragma unroll
      for (int kk = 0; kk < 2; kk++)
        af[m][kk] = *(const bf16x8*)(lgA + (wr * (MF * 16) + m * 16 + a15) * 128 +
                                     ((kk * 64 + a4 * 16) ^ swz));
#pragma unroll
    for (int n = 0; n < 4; n++)
#pragma unroll
      for (int kk = 0; kk < 2; kk++)
        bfr[n][kk] = *(const bf16x8*)(lgB + (wc * 64 + n * 16 + a15) * 128 +
                                      ((kk * 64 + a4 * 16) ^ swz));
#pragma unroll
    for (int kk = 0; kk < 2; kk++)
#pragma unroll
      for (int m = 0; m < MF; m++)
#pragma unroll
        for (int n = 0; n < 4; n++)
          acc[m][n] = __builtin_amdgcn_mfma_f32_16x16x32_bf16(af[m][kk], bfr[n][kk],
                                                              acc[m][n], 0, 0, 0);
    __syncthreads();
  }

#pragma unroll
  for (int m = 0; m < MF; m++) {
#pragma unroll
    for (int n = 0; n < 4; n++) {
      int gr0 = m0 + wr * (MF * 16) + m * 16 + a4 * 4;
      int col = n0 + wc * 64 + n * 16 + a15;
      float bv = bias[col];
      if constexpr (MODE == 2) {
        float* O = (float*)out;
#pragma unroll
        for (int j = 0; j < 4; j++)
          O[(size_t)(gr0 + j) * DM + col] = acc[m][n][j] + bv;
      } else if constexpr (MODE == 0) {
        uint16_t* O = (uint16_t*)out;
        int h = col >> 6, d = col & 63;
#pragma unroll
        for (int j = 0; j < 4; j++) {
          int gr = gr0 + j;
          int b = gr >> 11, s = gr & 2047;
          O[((size_t)(((b << 4) + h)) * SEQ + s) * HD + d] = f2bf((acc[m][n][j] + bv) * scale);
        }
      } else {
        // V'' layout: [bh][d][2048], within each 64-key group keys permuted:
        // pos = kb*32 + g*8 + ehi*4 + j  holds key k = kb*32 + 16*ehi + 4g + j
        uint16_t* O = (uint16_t*)out;
        int h = col >> 6, d = col & 63;
        int b = gr0 >> 11, s0 = gr0 & 2047;
        int it = s0 >> 6, s6 = s0 & 63;
        int pos = (s6 >> 5) * 32 + ((s6 >> 2) & 3) * 8 + ((s6 >> 4) & 1) * 4;
        uint64_t pk = 0;
#pragma unroll
        for (int j = 0; j < 4; j++)
          pk |= (uint64_t)f2bf(acc[m][n][j] + bv) << (16 * j);
        *(uint64_t*)&O[((size_t)(((b << 4) + h)) * HD + d) * SEQ + it * 64 + pos] = pk;
      }
    }
  }
}

#define CS_SCALE 0.180336880f  // log2(e)/sqrt(hd) folded into q

// flat grid 768, XCD-chunked: each XCD gets 96 consecutive (z,y,x) blocks
__global__ __launch_bounds__(256, 2) void gemm_qkv_kernel(
    const uint16_t* __restrict__ xb, const uint16_t* __restrict__ wtq,
    const uint16_t* __restrict__ wtk, const uint16_t* __restrict__ wtv,
    const float* __restrict__ bq, const float* __restrict__ bk,
    const float* __restrict__ bv, uint16_t* __restrict__ qo,
    uint16_t* __restrict__ ko, uint16_t* __restrict__ vto) {
  __shared__ __attribute__((aligned(16))) uint16_t lds[16384];  // 32 KB
  int id = blockIdx.x;
  int swz = (id & 7) * 96 + (id >> 3);
  int z = swz >> 8, r = swz & 255;
  int by = r >> 3, bx = r & 7;
  if (z == 0)      gemm_body<0, 4>(xb, wtq, bq, CS_SCALE, qo, lds, bx, by);
  else if (z == 1) gemm_body<0, 4>(xb, wtk, bk, 1.0f, ko, lds, bx, by);
  else             gemm_body<1, 4>(xb, wtv, bv, 1.0f, vto, lds, bx, by);
}

// flat grid 512, XCD-chunked (64 blocks per XCD)
__global__ __launch_bounds__(256, 2) void gemm_out_kernel(
    const uint16_t* __restrict__ ctx, const uint16_t* __restrict__ wto,
    const float* __restrict__ bo, float* __restrict__ out) {
  __shared__ __attribute__((aligned(16))) uint16_t lds[12288];  // 24 KB
  int id = blockIdx.x;
  int swz = (id & 7) * 64 + (id >> 3);
  int by = swz >> 3, bx = swz & 7;
  gemm_body<2, 2>(ctx, wto, bo, 1.0f, out, lds, bx, by);
}

// ---------------- attention (4-slot LDS ring: 2 tiles per barrier pair) ------
// q (pre-scaled by CS), k: [bh][s][64]   v'': [bh][d][2048 mu'-permuted]
// 512 blocks x 4 waves (128 q/block) -> 2 blocks/CU = 8 waves/CU = 2/SIMD.
// P = exp2(s') directly; scale cancels in O/l. Denominator via ones-MFMA.
// Ring: slots 0,1 computed while 2,3 staged (vmcnt(8) counted), then swap.
__global__ __launch_bounds__(256, 2) void attn_kernel(
    const uint16_t* __restrict__ qg, const uint16_t* __restrict__ kg,
    const uint16_t* __restrict__ vtg, uint16_t* __restrict__ ctx) {
  const int tid = threadIdx.x;
  const int w = tid >> 6, l = tid & 63;
  const int l15 = l & 15, g = l >> 4;
  // XCD swizzle: 64 consecutive wg per XCD -> 4 bh per XCD (KV fits L2)
  int id = blockIdx.x;
  int wg = (id & 7) * 64 + (id >> 3);
  int bh = wg >> 4, qb = wg & 15;
  const int q0 = qb * 128 + w * 32;
  const uint16_t* Qb = qg + (size_t)bh * SEQ * HD;
  const char* Kc = (const char*)(kg + (size_t)bh * SEQ * HD);
  const char* Vc = (const char*)(vtg + (size_t)bh * HD * SEQ);

  __shared__ __attribute__((aligned(16))) char Klds[4][8192];
  __shared__ __attribute__((aligned(16))) char Vlds[4][8192];

  // staging: 64 rows x 128B per tile; wave w covers rows w*16 + i*8 .. +8
  const int srow = l >> 3;                          // 0..7 (row&7 == srow)
  const int scolx = ((l & 7) * 16) ^ (srow << 4);   // swizzled source col

#define STAGE(BI, IT)                                                          \
  {                                                                            \
    const int it1_ = (IT);                                                     \
    _Pragma("unroll") for (int i = 0; i < 2; i++) {                            \
      int r = w * 16 + i * 8 + srow;                                           \
      gll16f(Kc + (size_t)(it1_ * 64 + r) * 128 + scolx,                       \
             &Klds[BI][w * 2048 + i * 1024], l);                               \
      gll16f(Vc + (size_t)r * (SEQ * 2) + it1_ * 128 + scolx,                  \
             &Vlds[BI][w * 2048 + i * 1024], l);                               \
    }                                                                          \
  }

  // Q B-frags (hoisted): bq[qs][ks] slot(g,e) = Q[q0+qs*16+l15][ks*32+g*8+e]
  bf16x8 bq[2][2];
#pragma unroll
  for (int qs = 0; qs < 2; qs++)
#pragma unroll
    for (int ks = 0; ks < 2; ks++)
      bq[qs][ks] = *(const bf16x8*)&Qb[(size_t)(q0 + qs * 16 + l15) * HD + ks * 32 + g * 8];

  f32x4 o[4][2];  // [dt][qs]
#pragma unroll
  for (int dt = 0; dt < 4; dt++)
#pragma unroll
    for (int qs = 0; qs < 2; qs++) o[dt][qs] = (f32x4){0.f, 0.f, 0.f, 0.f};
  f32x4 ol0 = {0.f, 0.f, 0.f, 0.f}, ol1 = {0.f, 0.f, 0.f, 0.f};  // denominators
  const int swz = (l15 & 7) << 4;               // read-side XOR
  const uint32_t ONE2 = 0x3F803F80u;            // 2x bf16 1.0
  const bf16x8 aones = mk8(ONE2, ONE2, ONE2, ONE2);

#define TILE_BODY(BI)                                                          \
  {                                                                            \
    /* K A-frags from LDS (swizzled) */                                        \
    bf16x8 ak[4][2];                                                           \
    _Pragma("unroll") for (int kt = 0; kt < 4; kt++)                           \
        _Pragma("unroll") for (int ks = 0; ks < 2; ks++)                       \
            ak[kt][ks] = *(const bf16x8*)&Klds[BI][(kt * 16 + l15) * 128 +     \
                                                   ((ks * 64 + g * 16) ^ swz)];\
    /* V A-frags (mu' baked into V''): single b128 per frag */                 \
    bf16x8 av[4][2];                                                           \
    _Pragma("unroll") for (int dt = 0; dt < 4; dt++)                           \
        _Pragma("unroll") for (int kb = 0; kb < 2; kb++)                       \
            av[dt][kb] = *(const bf16x8*)&Vlds[BI][(dt * 16 + l15) * 128 +     \
                                                   ((kb * 64 + g * 16) ^ swz)];\
    /* S^T[k][q] (q pre-scaled by CS) */                                       \
    f32x4 s[2][4];                                                             \
    _Pragma("unroll") for (int qs = 0; qs < 2; qs++)                           \
        _Pragma("unroll") for (int kt = 0; kt < 4; kt++)                       \
            s[qs][kt] = (f32x4){0.f, 0.f, 0.f, 0.f};                           \
    __builtin_amdgcn_s_setprio(1);                                             \
    _Pragma("unroll") for (int kt = 0; kt < 4; kt++)                           \
        _Pragma("unroll") for (int ks = 0; ks < 2; ks++) {                     \
      s[0][kt] = __builtin_amdgcn_mfma_f32_16x16x32_bf16(ak[kt][ks], bq[0][ks], s[0][kt], 0, 0, 0); \
      s[1][kt] = __builtin_amdgcn_mfma_f32_16x16x32_bf16(ak[kt][ks], bq[1][ks], s[1][kt], 0, 0, 0); \
    }                                                                          \
    __builtin_amdgcn_s_setprio(0);                                             \
    /* P = exp2(s); pack B-frags via mu' (no fma, no max, no cross-lane) */    \
    float p0[4][4], p1[4][4];                                                  \
    _Pragma("unroll") for (int kt = 0; kt < 4; kt++)                           \
        _Pragma("unroll") for (int j = 0; j < 4; j++) {                        \
      p0[kt][j] = EXP2F(s[0][kt][j]);                                          \
      p1[kt][j] = EXP2F(s[1][kt][j]);                                          \
    }                                                                          \
    bf16x8 bp0[2], bp1[2];                                                     \
    _Pragma("unroll") for (int kb = 0; kb < 2; kb++) {                         \
      bp0[kb] = mk8(cvtpk(p0[2 * kb][0], p0[2 * kb][1]),                       \
                    cvtpk(p0[2 * kb][2], p0[2 * kb][3]),                       \
                    cvtpk(p0[2 * kb + 1][0], p0[2 * kb + 1][1]),               \
                    cvtpk(p0[2 * kb + 1][2], p0[2 * kb + 1][3]));              \
      bp1[kb] = mk8(cvtpk(p1[2 * kb][0], p1[2 * kb][1]),                       \
                    cvtpk(p1[2 * kb][2], p1[2 * kb][3]),                       \
                    cvtpk(p1[2 * kb + 1][0], p1[2 * kb + 1][1]),               \
                    cvtpk(p1[2 * kb + 1][2], p1[2 * kb + 1][3]));              \
    }                                                                          \
    /* O^T += V . P ; l += 1 . P */                                            \
    __builtin_amdgcn_s_setprio(1);                                             \
    _Pragma("unroll") for (int dt = 0; dt < 4; dt++)                           \
        _Pragma("unroll") for (int kb = 0; kb < 2; kb++) {                     \
      o[dt][0] = __builtin_amdgcn_mfma_f32_16x16x32_bf16(av[dt][kb], bp0[kb], o[dt][0], 0, 0, 0); \
      o[dt][1] = __builtin_amdgcn_mfma_f32_16x16x32_bf16(av[dt][kb], bp1[kb], o[dt][1], 0, 0, 0); \
    }                                                                          \
    _Pragma("unroll") for (int kb = 0; kb < 2; kb++) {                         \
      ol0 = __builtin_amdgcn_mfma_f32_16x16x32_bf16(aones, bp0[kb], ol0, 0, 0, 0); \
      ol1 = __builtin_amdgcn_mfma_f32_16x16x32_bf16(aones, bp1[kb], ol1, 0, 0, 0); \
    }                                                                          \
    __builtin_amdgcn_s_setprio(0);                                             \
  }

  STAGE(0, 0);
  STAGE(1, 1);

  for (int it4 = 0; it4 < 8; ++it4) {
    int tb = it4 * 4;
    // iter A: compute tiles tb,tb+1 (slots 0,1); stage tb+2,tb+3 (slots 2,3)
    STAGE(2, tb + 2);
    STAGE(3, tb + 3);
    asm volatile("s_waitcnt vmcnt(8)\n\ts_barrier" ::: "memory");
    TILE_BODY(0);
    TILE_BODY(1);
    asm volatile("s_waitcnt lgkmcnt(0)\n\ts_barrier" ::: "memory");
    // iter B: compute tiles tb+2,tb+3 (slots 2,3); stage tb+4,tb+5 (slots 0,1)
    if (it4 < 7) {
      STAGE(0, tb + 4);
      STAGE(1, tb + 5);
      asm volatile("s_waitcnt vmcnt(8)\n\ts_barrier" ::: "memory");
    } else {
      asm volatile("s_waitcnt vmcnt(0)\n\ts_barrier" ::: "memory");
    }
    TILE_BODY(2);
    TILE_BODY(3);
    asm volatile("s_waitcnt lgkmcnt(0)\n\ts_barrier" ::: "memory");
  }
#undef TILE_BODY
#undef STAGE

  float inv0 = 1.0f / ol0[0];
  float inv1 = 1.0f / ol1[0];
  int b = bh >> 4, h = bh & 15;
  uint16_t* cr0 = ctx + (size_t)(b * SEQ + q0 + l15) * DM + h * HD + 4 * g;
  uint16_t* cr1 = cr0 + (size_t)16 * DM;
#pragma unroll
  for (int dt = 0; dt < 4; dt++) {
    u32x2 wv;
    wv[0] = cvtpk(o[dt][0][0] * inv0, o[dt][0][1] * inv0);
    wv[1] = cvtpk(o[dt][0][2] * inv0, o[dt][0][3] * inv0);
    *(u32x2*)&cr0[dt * 16] = wv;
    u32x2 wv2;
    wv2[0] = cvtpk(o[dt][1][0] * inv1, o[dt][1][1] * inv1);
    wv2[1] = cvtpk(o[dt][1][2] * inv1, o[dt][1][3] * inv1);
    *(u32x2*)&cr1[dt * 16] = wv2;
  }
}

extern "C" void kernel_launch(void* const* d_in, const int* in_sizes, int n_in,
                              void* d_out, int out_size, void* d_ws, size_t ws_size,
                              hipStream_t stream) {
  const float* x  = (const float*)d_in[0];
  const float* Wq = (const float*)d_in[1];
  const float* bq = (const float*)d_in[2];
  const float* Wk = (const float*)d_in[3];
  const float* bk = (const float*)d_in[4];
  const float* Wv = (const float*)d_in[5];
  const float* bv = (const float*)d_in[6];
  const float* Wo = (const float*)d_in[7];
  const float* bo = (const float*)d_in[8];

  char* ws = (char*)d_ws;
  uint16_t* xb  = (uint16_t*)(ws);               // 8 MB (aliased as ctx later)
  uint16_t* wtq = (uint16_t*)(ws + 8388608);     // 2 MB each
  uint16_t* wtk = (uint16_t*)(ws + 10485760);
  uint16_t* wtv = (uint16_t*)(ws + 12582912);
  uint16_t* wto = (uint16_t*)(ws + 14680064);
  uint16_t* qb  = (uint16_t*)(ws + 16777216);    // 8 MB
  uint16_t* kb  = (uint16_t*)(ws + 25165824);    // 8 MB
  uint16_t* vtb = (uint16_t*)(ws + 33554432);    // 8 MB
  uint16_t* ctx = xb;  // xb dead after gemm_qkv; reuse for ctx

  prep_kernel<<<dim3(8192), dim3(256), 0, stream>>>(
      x, xb, Wq, Wk, Wv, Wo, wtq, wtk, wtv, wto);
  gemm_qkv_kernel<<<dim3(768), dim3(256), 0, stream>>>(
      xb, wtq, wtk, wtv, bq, bk, bv, qb, kb, vtb);
  attn_kernel<<<dim3(512), dim3(256), 0, stream>>>(qb, kb, vtb, ctx);
  gemm_out_kernel<<<dim3(512), dim3(256), 0, stream>>>(ctx, wto, bo, (float*)d_out);
}